// Round 6
// baseline (315.141 us; speedup 1.0000x reference)
//
#include <hip/hip_runtime.h>

typedef unsigned short u16;
typedef unsigned int u32;
typedef __attribute__((ext_vector_type(8))) short bf16x8;
typedef __attribute__((ext_vector_type(4))) float f32x4;
typedef __attribute__((ext_vector_type(4))) u16 u16x4;

constexpr int BATCH  = 4096;
constexpr int SEQ    = 512;
constexpr int HID    = 64;
constexpr int EMB_N4 = 50257 * 64 / 4;   // 804112 float4 groups in emb

__device__ __forceinline__ float bf2f(u16 u) {
  union { u32 i; float f; } c; c.i = ((u32)u) << 16; return c.f;
}
__device__ __forceinline__ u16 f2bf(float f) {
  union { float f; u32 i; } c; c.f = f;
  u32 u = c.i;
  u += 0x7fffu + ((u >> 16) & 1u);   // RNE (finite inputs only)
  return (u16)(u >> 16);
}

#define MFMA16(a, b, c) __builtin_amdgcn_mfma_f32_16x16x32_bf16(a, b, c, 0, 0, 0)

// async global->LDS, 16B per lane, dest = lds_base + lane*16
__device__ __forceinline__ void glds16(const u16* g, u16* l) {
  __builtin_amdgcn_global_load_lds(
      (const __attribute__((address_space(1))) u32*)g,
      (__attribute__((address_space(3))) u32*)l, 16, 0, 0);
}

// unpack 8 packed u32 (hi16 | lo16<<16) -> hi bf16x8, lo bf16x8
__device__ __forceinline__ void unpack2(uint4 a, uint4 b, bf16x8& hi, bf16x8& lo) {
  union { u32 u[4]; bf16x8 v; } H, L;
  H.u[0] = __builtin_amdgcn_perm(a.y, a.x, 0x05040100u);
  H.u[1] = __builtin_amdgcn_perm(a.w, a.z, 0x05040100u);
  H.u[2] = __builtin_amdgcn_perm(b.y, b.x, 0x05040100u);
  H.u[3] = __builtin_amdgcn_perm(b.w, b.z, 0x05040100u);
  L.u[0] = __builtin_amdgcn_perm(a.y, a.x, 0x07060302u);
  L.u[1] = __builtin_amdgcn_perm(a.w, a.z, 0x07060302u);
  L.u[2] = __builtin_amdgcn_perm(b.y, b.x, 0x07060302u);
  L.u[3] = __builtin_amdgcn_perm(b.w, b.z, 0x07060302u);
  hi = H.v; lo = L.v;
}

// ---- Prep: emb fp32 -> bf16; W_ih -> hi; W_hh -> hi+lo; zero BN acc.
__global__ __launch_bounds__(256) void prep_kernel(
    const float4* __restrict__ emb4, const float* __restrict__ Wih,
    const float* __restrict__ Whh, u16x4* __restrict__ emb_bf4,
    u16* __restrict__ wih_hi, u16* __restrict__ whh_hi, u16* __restrict__ whh_lo,
    float* __restrict__ bn_acc)
{
  int gid = blockIdx.x * 256 + threadIdx.x;
  if (gid < EMB_N4) {
    float4 v = emb4[gid];
    u16x4 o;
    o.x = f2bf(v.x); o.y = f2bf(v.y); o.z = f2bf(v.z); o.w = f2bf(v.w);
    emb_bf4[gid] = o;
  } else if (gid < EMB_N4 + 1024) {
    int i0 = (gid - EMB_N4) * 4;
    #pragma unroll
    for (int k = 0; k < 4; ++k) {
      int i = i0 + k;
      wih_hi[i] = f2bf(Wih[i]);
      float w = Whh[i];
      u16 hi = f2bf(w);
      whh_hi[i] = hi;
      whh_lo[i] = f2bf(w - bf2f(hi));
    }
  } else if (gid < EMB_N4 + 1024 + 128) {
    bn_acc[gid - (EMB_N4 + 1024)] = 0.f;   // ws is poisoned 0xAA every call
  }
}

// ---- Kernel 1: fused embedding-gather + input projection + tanh-RNN scan.
// 256 blocks x 256 threads; block owns 16 batch rows; wave w owns feats [16w,16w+16).
// emb staged by WAVE 0 ONLY via global_load_lds into an 8-slot LDS ring,
// 7 steps ahead; wave0's barrier waits vmcnt(12) (next slot complete, rest in
// flight); waves 1-3 have zero vmem in the loop (lgkmcnt-only barrier).
// h carried as packed u32 (bf16 hi | lo<<16) in swizzled double-buffered LDS.
__global__ __launch_bounds__(256, 1) void rnn_scan_kernel(
    const int* __restrict__ xx, const u16* __restrict__ emb_bf,
    const u16* __restrict__ wih_hi, const u16* __restrict__ whh_hi,
    const u16* __restrict__ whh_lo,
    const float* __restrict__ b_ih, const float* __restrict__ b_hh,
    float* __restrict__ hT /* [HID][BATCH] */, float* __restrict__ bn_acc)
{
  __shared__ u32 hpk[2 * 1024];    // 8 KB: [buf][m=16][c=64] packed u32
  __shared__ u16 ring[8 * 1024];   // 16 KB: 8 slots x 2 KB (16 rows x 128 B bf16)
  const int tid = threadIdx.x;
  const int w = tid >> 6;
  const int L = tid & 63;
  const int n = L & 15;
  const int q = L >> 4;
  const int R0 = blockIdx.x << 4;
  const int feat = (w << 4) + n;

  // h0 = 0: zero buffer 0 (4 KB = 256 x 16 B)
  ((int4*)hpk)[tid] = int4{0, 0, 0, 0};

  // Constant B-fragments (weights) in registers.
  bf16x8 Bih0 = *(const bf16x8*)(wih_hi + feat * 64 +      8 * q);
  bf16x8 Bih1 = *(const bf16x8*)(wih_hi + feat * 64 + 32 + 8 * q);
  bf16x8 Bh0  = *(const bf16x8*)(whh_hi + feat * 64 +      8 * q);
  bf16x8 Bh1  = *(const bf16x8*)(whh_hi + feat * 64 + 32 + 8 * q);
  bf16x8 Bl0  = *(const bf16x8*)(whh_lo + feat * 64 +      8 * q);
  bf16x8 Bl1  = *(const bf16x8*)(whh_lo + feat * 64 + 32 + 8 * q);
  const float bias = b_ih[feat] + b_hh[feat];

  // h read: lane (m=n, q) wants k-runs 8q..8q+7 and 32+8q..+7, swizzle bit4 by (m>>2)&1
  const int sw   = ((n >> 2) & 1) << 4;
  const int roff = n * 64 + ((8 * q) ^ sw);        // u32 index of k-low run
  // h write: m = 4q+r, col = feat ^ ((q&1)<<4)  (same swizzle: m>>2 == q)
  const int wcol = feat ^ ((q & 1) << 4);
  // ring read offset (u16 units): lane (n,q) -> (q*16+n)*8
  const int e0off = (q * 16 + n) * 8;

  const int4* x4 = (const int4*)(xx + (R0 + n) * SEQ);   // idx rows per lane-n
  int4 JA = {0,0,0,0}, JB = {0,0,0,0};                   // wave0 only

  if (w == 0) {
    int4 K0 = x4[0];
    int4 K1 = x4[1];
    const int pre[8] = {K0.x, K0.y, K0.z, K0.w, K1.x, K1.y, K1.z, 0};
    #pragma unroll
    for (int p = 0; p < 7; ++p) {            // stage steps 0..6 into slots 0..6
      const u16* gp = emb_bf + (long)pre[p] * 64 + q * 8;
      u16* lp = ring + p * 1024;
      glds16(gp, lp);            // elements  0..31 (this lane: 8q..8q+7)
      glds16(gp + 32, lp + 512); // elements 32..63 (this lane: 32+8q..32+8q+7)
    }
    JA = K1;                                  // idx group t+1 (for step 4t+7)
    JB = x4[2];                               // idx group t+2
  }

  __syncthreads();   // drains wave0's vmcnt -> slots 0..6 + zero-init visible

  for (int t = 0; t < SEQ / 4; ++t) {
    const int sbase = (t & 1) << 2;           // 4t mod 8
    int4 JC = {0,0,0,0};

    #pragma unroll
    for (int u = 0; u < 4; ++u) {
      const int cur = u & 1;                  // s&1 (4t even)
      const int slot_rd  = sbase + u;
      const int slot_dma = (sbase + u + 7) & 7;   // = (s-1)&7, freed last barrier

      // emb fragments from the LDS ring (no global jitter on consume path)
      const u16* rp = ring + slot_rd * 1024;
      bf16x8 ae0 = *(const bf16x8*)(rp + e0off);
      bf16x8 ae1 = *(const bf16x8*)(rp + 512 + e0off);

      // h fragments: 4 x b128 packed u32, then VALU unpack (per-SIMD, off LDS unit)
      const u32* hb = hpk + cur * 1024;
      uint4 vl0 = *(const uint4*)(hb + roff);
      uint4 vl1 = *(const uint4*)(hb + roff + 4);
      uint4 vh0 = *(const uint4*)(hb + roff + 32);
      uint4 vh1 = *(const uint4*)(hb + roff + 36);
      bf16x8 ah0, al0, ah1, al1;
      unpack2(vl0, vl1, ah0, al0);
      unpack2(vh0, vh1, ah1, al1);

      f32x4 C1 = {bias, bias, bias, bias};
      C1 = MFMA16(ae0, Bih0, C1);
      C1 = MFMA16(ae1, Bih1, C1);

      f32x4 Cx = {0.f, 0.f, 0.f, 0.f};
      f32x4 Cy = {0.f, 0.f, 0.f, 0.f};
      f32x4 Cz = {0.f, 0.f, 0.f, 0.f};
      Cx = MFMA16(ah0, Bh0, Cx);  Cx = MFMA16(al0, Bh0, Cx);
      Cy = MFMA16(ah1, Bh1, Cy);  Cy = MFMA16(al1, Bh1, Cy);
      Cz = MFMA16(ah0, Bl0, Cz);  Cz = MFMA16(ah1, Bl1, Cz);

      // wave0: stage step s+7 into the slot freed at the last barrier
      if (w == 0) {
        const int idxv = (u == 0) ? JA.w : (u == 1) ? JB.x : (u == 2) ? JB.y : JB.z;
        const u16* gp = emb_bf + (long)idxv * 64 + q * 8;
        u16* lp = ring + slot_dma * 1024;
        glds16(gp, lp);
        glds16(gp + 32, lp + 512);
        if (u == 0) {
          int tc = (t + 3 < SEQ / 4) ? t + 3 : SEQ / 4 - 1;
          JC = x4[tc];
        }
      }

      u32* wb = hpk + (cur ^ 1) * 1024;
      float th4[4];
      #pragma unroll
      for (int r = 0; r < 4; ++r) {
        float v = (C1[r] + Cx[r]) + (Cy[r] + Cz[r]);
        // tanh(v) = 1 - 2/(1 + 2^(2*log2e*v)); exact saturation at +-1
        float ex = __builtin_amdgcn_exp2f(2.8853900817779268f * v);
        float th = fmaf(-2.0f, __builtin_amdgcn_rcpf(ex + 1.0f), 1.0f);
        th4[r] = th;
        // truncated hi/lo split packed into one u32 (hi in low16, lo in high16)
        u32 tb = __float_as_uint(th);
        u32 remb = __float_as_uint(th - __uint_as_float(tb & 0xffff0000u));
        u32 packed = __builtin_amdgcn_perm(remb, tb, 0x07060302u);
        wb[((q << 2) + r) * 64 + wcol] = packed;
      }

      if (t == SEQ / 4 - 1 && u == 3) {   // epilogue: h_n out + BN partial sums
        float s1 = 0.f, s2 = 0.f;
        #pragma unroll
        for (int r = 0; r < 4; ++r) {
          hT[feat * BATCH + R0 + (q << 2) + r] = th4[r];
          s1 += th4[r];
          s2 = fmaf(th4[r], th4[r], s2);
        }
        s1 += __shfl_xor(s1, 16, 64);  s2 += __shfl_xor(s2, 16, 64);
        s1 += __shfl_xor(s1, 32, 64);  s2 += __shfl_xor(s2, 32, 64);
        if (q == 0) {
          atomicAdd(bn_acc + feat, s1);
          atomicAdd(bn_acc + 64 + feat, s2);
        }
      }

      // wave0: complete next slot's DMA (vmcnt 12 keeps ~6 steps of loads in
      // flight); others: LDS-visibility-only barrier, zero vmem waits.
      if (w == 0)
        asm volatile("s_waitcnt vmcnt(12) lgkmcnt(0)\n\ts_barrier" ::: "memory");
      else
        asm volatile("s_waitcnt lgkmcnt(0)\n\ts_barrier" ::: "memory");
    }
    if (w == 0) { JA = JB; JB = JC; }
  }
}

// ---- Kernel 2: BN fold (from accumulated sums) + logits GEMV. fp32 out.
__global__ __launch_bounds__(256) void head_kernel(
    const float* __restrict__ hT, const float* __restrict__ bn_acc,
    const float* __restrict__ gamma, const float* __restrict__ beta,
    const float* __restrict__ Wfc, const float* __restrict__ bfc,
    float* __restrict__ out)
{
  __shared__ float sc[64], sh[64];
  const int tid = threadIdx.x;
  if (tid < 64) {
    float mean = bn_acc[tid] * (1.0f / BATCH);
    float var  = bn_acc[64 + tid] * (1.0f / BATCH) - mean * mean;  // biased
    float inv  = rsqrtf(var + 1e-5f);
    float s    = gamma[tid] * inv;
    sc[tid] = s;
    sh[tid] = beta[tid] - mean * s;
  }
  __syncthreads();
  const int b = blockIdx.x * 256 + tid;
  float acc[5];
  #pragma unroll
  for (int c = 0; c < 5; ++c) acc[c] = bfc[c];
  for (int j = 0; j < HID; ++j) {
    float hv  = hT[j * BATCH + b];
    float hat = fmaf(hv, sc[j], sh[j]);
    #pragma unroll
    for (int c = 0; c < 5; ++c) acc[c] = fmaf(hat, Wfc[c * 64 + j], acc[c]);
  }
  #pragma unroll
  for (int c = 0; c < 5; ++c) out[b * 5 + c] = acc[c];
}

extern "C" void kernel_launch(void* const* d_in, const int* in_sizes, int n_in,
                              void* d_out, int out_size, void* d_ws, size_t ws_size,
                              hipStream_t stream)
{
  const int*   x     = (const int*)d_in[0];
  const float* emb   = (const float*)d_in[1];
  const float* W_ih  = (const float*)d_in[2];
  const float* W_hh  = (const float*)d_in[3];
  const float* b_ih  = (const float*)d_in[4];
  const float* b_hh  = (const float*)d_in[5];
  const float* gamma = (const float*)d_in[6];
  const float* beta  = (const float*)d_in[7];
  const float* W_fc  = (const float*)d_in[8];
  const float* b_fc  = (const float*)d_in[9];

  char* ws = (char*)d_ws;
  float* hT     = (float*)ws;                 // [64][4096] fp32, 1 MB
  float* bn_acc = (float*)(ws + 1048576);     // [2][64] fp32 atomics
  u16*   emb_bf = (u16*)(ws + 1049088);       // [50257][64] bf16, 6.43 MB
  u16*   wih_hi = (u16*)(ws + 7481984);
  u16*   whh_hi = (u16*)(ws + 7490176);
  u16*   whh_lo = (u16*)(ws + 7498368);

  const int prep_items = EMB_N4 + 1024 + 128;
  prep_kernel<<<dim3((prep_items + 255) / 256), dim3(256), 0, stream>>>(
      (const float4*)emb, W_ih, W_hh, (u16x4*)emb_bf, wih_hi, whh_hi, whh_lo, bn_acc);
  rnn_scan_kernel<<<dim3(BATCH / 16), dim3(256), 0, stream>>>(
      x, emb_bf, wih_hi, whh_hi, whh_lo, b_ih, b_hh, hT, bn_acc);
  head_kernel<<<dim3(BATCH / 256), dim3(256), 0, stream>>>(
      hT, bn_acc, gamma, beta, W_fc, b_fc, (float*)d_out);
}